// Round 15
// baseline (1099.706 us; speedup 1.0000x reference)
//
#include <hip/hip_runtime.h>
#include <stdint.h>

typedef __bf16 bf16;
typedef __bf16 bf16x8 __attribute__((ext_vector_type(8)));
typedef __bf16 bf16x4 __attribute__((ext_vector_type(4)));
typedef float f32x4 __attribute__((ext_vector_type(4)));

#define WIN 8

__device__ __forceinline__ float sigm(float x) { return 1.0f / (1.0f + __expf(-x)); }
__device__ __forceinline__ float tanhfast(float x) { return 2.0f / (1.0f + __expf(-2.0f * x)) - 1.0f; }

__device__ __forceinline__ void gload16(const void* g, void* l) {
    __builtin_amdgcn_global_load_lds((const __attribute__((address_space(1))) void*)g,
                                     (__attribute__((address_space(3))) void*)l, 16, 0, 0);
}

struct StepArgs {
    const bf16* A1;      // GEMM A source (X0 for MODE0, h_prev for MODE1, x-slot for MODE2)
    const bf16* A2;      // MODE2 h_prev (K 1024..1535)
    const bf16* W;       // B^T operand (weights; row = output col)
    const float* bias;
    const bf16* P0;      // MODE1: P0 [4096][2048], col = u*4 + gate (gate-interleaved)
    float* Cst;          // cell state [4096,512] f32
    bf16* Hout;          // output h
    float* Hf32;         // optional f32 copy of h
    const bf16* Hprev;   // h_prev for masked carry
    int l;               // window slot (for mask)
    int firstStep;
};

// 256x256 tile, 8 waves (2M x 4N, wave tile 128x64). K consumed in HALVES (K=32).
// 4-slot LDS ring (slot = A 256x32 + B 256x32 = 32KB): consume half h while h+1..h+3
// are staged/in-flight. Publication of h+1 = counted vmcnt(8) (h+2/h+3's 8 loads stay
// in flight -- never drains in steady state) + ONE barrier per half. Issue->wait
// distance = 2 halves (~1200cy) > HBM latency: the true T4 depth that R11's shallow
// variant lacked. Per-acc MFMA order identical to R9/R14 (bit-identical results).
// 64B-row swizzle: key(r)=((r^(r>>2))&3) applied as the same involution on the
// staging source chunk and the ds_read slot (2-way bank aliasing = free).
// MODE 0: plain GEMM (P0 = X0 @ W^T), gate-interleaved cols, output stride 2048
// MODE 1: layer-0 LSTM step: acc = h@whh^T (K=512), epilogue adds P0 gather + bias
// MODE 2: layer-1 LSTM step: acc = [x,h]@[wih|whh]^T (K=1536), epilogue adds bias
template<int MODE>
__global__ __launch_bounds__(512, 2)
void step_pair(StepArgs fa, StepArgs ba) {
    const StepArgs a = blockIdx.z ? ba : fa;
    __shared__ alignas(16) char lds[131072];   // 4 ring slots x 32KB

    constexpr int SA1 = (MODE == 0) ? 512 : 1024;   // A row stride
    constexpr int SW  = (MODE == 2) ? 1536 : 512;   // B-operand row stride
    constexpr int SH  = (MODE == 0) ? 2048 : (MODE == 1 ? 1024 : 512);
    constexpr int SHP = (MODE == 1) ? 1024 : 512;   // Hprev stride

    const int tid = threadIdx.x;
    const int w = tid >> 6;
    const int lane = tid & 63;
    const int wm = w >> 2, wn = w & 3;
    const int bx = blockIdx.x, by = blockIdx.y;
    const int rowBase = bx * 256;

    int H;  // number of K=32 halves
    if (MODE == 0) H = 16;
    else if (MODE == 1) H = a.firstStep ? 0 : 16;
    else H = a.firstStep ? 32 : 48;

    // ---- staging lane geometry: one gload16 covers 16 rows x 64B ----
    const int q = lane >> 2;                               // row within 16-row chunk
    const int soff = ((lane & 3) ^ ((q ^ (q >> 2)) & 3)) * 8;  // pre-swizzled src chunk (elems)

    const bf16* aP[2];
    const bf16* a2P[2];
    const bf16* bP[2];
#pragma unroll
    for (int j = 0; j < 2; ++j) {
        const int r = w * 32 + j * 16 + q;      // LDS row 0..255 this lane writes
        const int n = rowBase + r;
        aP[j] = a.A1 ? (a.A1 + (size_t)n * SA1 + soff) : (const bf16*)0;
        if (MODE == 2) a2P[j] = a.A2 ? (a.A2 + (size_t)n * 512 + soff) : (const bf16*)0;
        int wr;
        if (MODE == 0) wr = (r & 3) * 512 + by * 64 + (r >> 2);   // gate-interleave cols
        else wr = ((r & 63) >> 4) * 512 + by * 64 + (r >> 6) * 16 + (r & 15);
        bP[j] = a.W + (size_t)wr * SW + soff;
    }

    // ---- compute-side fragment offsets (64B rows, swizzled slot) ----
    const int l15 = lane & 15, l4 = lane >> 4;
    const int rkey = (l4 ^ ((l15 ^ (l15 >> 2)) & 3)) << 4;
    const int aOff = (wm * 128 + l15) * 64 + rkey;       // + m*1024
    const int bOff = (wn * 64 + l15) * 64 + rkey;        // + n*1024

    f32x4 acc[8][4];
    const f32x4 zf = {0.f, 0.f, 0.f, 0.f};
#pragma unroll
    for (int m = 0; m < 8; ++m)
#pragma unroll
        for (int n = 0; n < 4; ++n) acc[m][n] = zf;

    auto STAGE = [&](int h) {
        char* Sd = lds + (h & 3) * 32768;
        const int ke = h * 32;
#pragma unroll
        for (int j = 0; j < 2; ++j) {
            const bf16* srcA;
            if (MODE == 2) srcA = (h < 32) ? (aP[j] + ke) : (a2P[j] + (ke - 1024));
            else srcA = aP[j] + ke;
            gload16(srcA, Sd + (w * 32 + j * 16) * 64);
            gload16(bP[j] + ke, Sd + 16384 + (w * 32 + j * 16) * 64);
        }
    };

    if (H > 0) {
        STAGE(0);
        if (H > 1) STAGE(1);
        if (H > 2) STAGE(2);
        if (H > 2)      asm volatile("s_waitcnt vmcnt(8)" ::: "memory");
        else if (H > 1) asm volatile("s_waitcnt vmcnt(4)" ::: "memory");
        else            asm volatile("s_waitcnt vmcnt(0)" ::: "memory");
        __builtin_amdgcn_s_barrier();

        for (int h = 0; h < H; ++h) {
            const char* Sl = lds + (h & 3) * 32768;
            bf16x8 af[4], bv[4];

            // ---- phase A: (m 0..3) x bv ----
#pragma unroll
            for (int n = 0; n < 4; ++n)
                bv[n] = *(const bf16x8*)(Sl + 16384 + bOff + n * 1024);
#pragma unroll
            for (int i = 0; i < 4; ++i)
                af[i] = *(const bf16x8*)(Sl + aOff + i * 1024);
            asm volatile("s_waitcnt lgkmcnt(0)" ::: "memory");
            __builtin_amdgcn_sched_barrier(0);
            __builtin_amdgcn_s_setprio(1);
#pragma unroll
            for (int i = 0; i < 4; ++i)
#pragma unroll
                for (int n = 0; n < 4; ++n)
                    acc[i][n] = __builtin_amdgcn_mfma_f32_16x16x32_bf16(af[i], bv[n], acc[i][n], 0, 0, 0);
            __builtin_amdgcn_s_setprio(0);
            __builtin_amdgcn_sched_barrier(0);

            // ---- phase B: (m 4..7) x bv; issue stage(h+3); publish h+1 ----
            if (h + 3 < H) STAGE(h + 3);
#pragma unroll
            for (int i = 0; i < 4; ++i)
                af[i] = *(const bf16x8*)(Sl + aOff + (4 + i) * 1024);
            asm volatile("s_waitcnt lgkmcnt(0)" ::: "memory");
            __builtin_amdgcn_sched_barrier(0);
            __builtin_amdgcn_s_setprio(1);
#pragma unroll
            for (int i = 0; i < 4; ++i)
#pragma unroll
                for (int n = 0; n < 4; ++n)
                    acc[4 + i][n] = __builtin_amdgcn_mfma_f32_16x16x32_bf16(af[i], bv[n], acc[4 + i][n], 0, 0, 0);
            __builtin_amdgcn_s_setprio(0);
            __builtin_amdgcn_sched_barrier(0);

            if (h + 1 < H) {
                if (h + 3 < H)      asm volatile("s_waitcnt vmcnt(8)" ::: "memory");
                else if (h + 2 < H) asm volatile("s_waitcnt vmcnt(4)" ::: "memory");
                else                asm volatile("s_waitcnt vmcnt(0)" ::: "memory");
                __builtin_amdgcn_s_barrier();   // publishes slot h+1; one barrier per half
            }
        }
    }

    if (MODE == 0) {
#pragma unroll
        for (int m = 0; m < 8; ++m)
#pragma unroll
            for (int n = 0; n < 4; ++n) {
                const int col = by * 256 + wn * 64 + n * 16 + l15;
#pragma unroll
                for (int e = 0; e < 4; ++e) {
                    const int row = rowBase + wm * 128 + m * 16 + l4 * 4 + e;
                    a.Hout[(size_t)row * SH + col] = (bf16)acc[m][n][e];
                }
            }
        return;
    }

    // ---- LSTM epilogue: n-frag index = gate (i,f,g,o), unit = by*64 + wn*16 + l15 ----
    const int u = by * 64 + wn * 16 + l15;
    const float bi = a.bias[u];
    const float bff = a.bias[512 + u];
    const float bg = a.bias[1024 + u];
    const float bo = a.bias[1536 + u];
#pragma unroll
    for (int m = 0; m < 8; ++m) {
        const int n0 = rowBase + wm * 128 + m * 16 + l4 * 4;
        bf16x4 pg[4];
        if (MODE == 1) {
            const int s0 = n0 >> 3;
            int pc = s0 + a.l - WIN;
            pc = pc < 0 ? 0 : (pc > 511 ? 511 : pc);
            const size_t base = ((size_t)pc * 8 + (n0 & 7)) * 2048 + u * 4;
#pragma unroll
            for (int e = 0; e < 4; ++e)
                pg[e] = *(const bf16x4*)(a.P0 + base + (size_t)e * 2048);
        }
#pragma unroll
        for (int e = 0; e < 4; ++e) {
            const int n = n0 + e;
            const int s = n >> 3;
            const int p = s + a.l - WIN;
            const bool valid = ((unsigned)p < 512u);
            float gi = acc[m][0][e] + bi;
            float gf = acc[m][1][e] + bff;
            float gg = acc[m][2][e] + bg;
            float go = acc[m][3][e] + bo;
            if (MODE == 1) {
                gi += (float)pg[e][0];
                gf += (float)pg[e][1];
                gg += (float)pg[e][2];
                go += (float)pg[e][3];
            }
            const float cold = a.firstStep ? 0.0f : a.Cst[(size_t)n * 512 + u];
            const float cnew = sigm(gf) * cold + sigm(gi) * tanhfast(gg);
            const float hnew = sigm(go) * tanhfast(cnew);
            float hv, cv;
            if (valid) { hv = hnew; cv = cnew; }
            else {
                hv = a.Hprev ? (float)a.Hprev[(size_t)n * SHP + u] : 0.0f;
                cv = cold;
            }
            a.Cst[(size_t)n * 512 + u] = cv;
            a.Hout[(size_t)n * SH + u] = (bf16)hv;
            if (a.Hf32) a.Hf32[(size_t)n * 512 + u] = hv;
        }
    }
}

__global__ void embed_kernel(const int* __restrict__ tok, const float* __restrict__ tbl,
                             bf16* __restrict__ X0) {
    const int n = blockIdx.x;
    const int t = tok[n];
    const float4 v = ((const float4*)(tbl + (size_t)t * 512))[threadIdx.x];
    bf16x4 o = {(bf16)v.x, (bf16)v.y, (bf16)v.z, (bf16)v.w};
    ((bf16x4*)(X0 + (size_t)n * 512))[threadIdx.x] = o;
}

// Fused weight prep: y=0..3 -> cvt 2048x512 (wih0f, wih0b, whh0f, whh0b);
// y=4..5 -> build w1 [2048][1536] = [wih1 | whh1].
__global__ void prep_kernel(const float* __restrict__ wih0f, const float* __restrict__ wih0b,
                            const float* __restrict__ whh0f, const float* __restrict__ whh0b,
                            const float* __restrict__ wih1f, const float* __restrict__ whh1f,
                            const float* __restrict__ wih1b, const float* __restrict__ whh1b,
                            bf16* __restrict__ d0, bf16* __restrict__ d1,
                            bf16* __restrict__ d2, bf16* __restrict__ d3,
                            bf16* __restrict__ d4, bf16* __restrict__ d5) {
    const int r = blockIdx.x;
    const int y = blockIdx.y;
    if (y < 4) {
        const float* s = (y == 0) ? wih0f : (y == 1) ? wih0b : (y == 2) ? whh0f : whh0b;
        bf16* d = (y == 0) ? d0 : (y == 1) ? d1 : (y == 2) ? d2 : d3;
        const int k = threadIdx.x * 2;
        const float2 v = *(const float2*)(s + (size_t)r * 512 + k);
        d[(size_t)r * 512 + k] = (bf16)v.x;
        d[(size_t)r * 512 + k + 1] = (bf16)v.y;
    } else {
        const float* wih = (y == 4) ? wih1f : wih1b;
        const float* whh = (y == 4) ? whh1f : whh1b;
        bf16* d = (y == 4) ? d4 : d5;
        for (int k = threadIdx.x; k < 1536; k += 256) {
            const float v = (k < 1024) ? wih[(size_t)r * 1024 + k] : whh[(size_t)r * 512 + (k - 1024)];
            d[(size_t)r * 1536 + k] = (bf16)v;
        }
    }
}

__global__ void combine_kernel(const float* __restrict__ hf, const float* __restrict__ hb,
                               float* __restrict__ out) {
    const int i = blockIdx.x * 256 + threadIdx.x;
    const float4 x = ((const float4*)hf)[i];
    const float4 y = ((const float4*)hb)[i];
    float4 r;
    r.x = (x.x + y.x) * 0.5f;
    r.y = (x.y + y.y) * 0.5f;
    r.z = (x.z + y.z) * 0.5f;
    r.w = (x.w + y.w) * 0.5f;
    ((float4*)out)[i] = r;
}

extern "C" void kernel_launch(void* const* d_in, const int* in_sizes, int n_in,
                              void* d_out, int out_size, void* d_ws, size_t ws_size,
                              hipStream_t stream) {
    (void)in_sizes; (void)n_in; (void)out_size;
    const int*   tok   = (const int*)d_in[0];
    const float* tbl   = (const float*)d_in[1];
    const float* wih0f = (const float*)d_in[2];
    const float* whh0f = (const float*)d_in[3];
    const float* b0f   = (const float*)d_in[4];
    const float* wih0b = (const float*)d_in[5];
    const float* whh0b = (const float*)d_in[6];
    const float* b0b   = (const float*)d_in[7];
    const float* wih1f = (const float*)d_in[8];
    const float* whh1f = (const float*)d_in[9];
    const float* b1f   = (const float*)d_in[10];
    const float* wih1b = (const float*)d_in[11];
    const float* whh1b = (const float*)d_in[12];
    const float* b1b   = (const float*)d_in[13];

    char* ws = (char*)d_ws;
    size_t off = 0;
    auto alloc = [&](size_t bytes) -> char* {
        char* p = ws + off;
        off += (bytes + 255) & ~(size_t)255;
        return p;
    };
    bf16* wih0f_b = (bf16*)alloc((size_t)2048 * 512 * 2);
    bf16* wih0b_b = (bf16*)alloc((size_t)2048 * 512 * 2);
    bf16* whh0f_b = (bf16*)alloc((size_t)2048 * 512 * 2);
    bf16* whh0b_b = (bf16*)alloc((size_t)2048 * 512 * 2);
    bf16* w1f_b   = (bf16*)alloc((size_t)2048 * 1536 * 2);
    bf16* w1b_b   = (bf16*)alloc((size_t)2048 * 1536 * 2);
    bf16* X0      = (bf16*)alloc((size_t)4096 * 512 * 2);
    bf16* P0f     = (bf16*)alloc((size_t)4096 * 2048 * 2);
    bf16* P0b     = (bf16*)alloc((size_t)4096 * 2048 * 2);
    bf16* X1      = (bf16*)alloc((size_t)17 * 4096 * 1024 * 2);
    float* c0f    = (float*)alloc((size_t)4096 * 512 * 4);
    float* c0b    = (float*)alloc((size_t)4096 * 512 * 4);
    bf16* h1f0    = (bf16*)alloc((size_t)4096 * 512 * 2);
    bf16* h1f1    = (bf16*)alloc((size_t)4096 * 512 * 2);
    bf16* h1b0    = (bf16*)alloc((size_t)4096 * 512 * 2);
    bf16* h1b1    = (bf16*)alloc((size_t)4096 * 512 * 2);
    float* hf32f  = (float*)alloc((size_t)4096 * 512 * 4);
    float* hf32b  = (float*)alloc((size_t)4096 * 512 * 4);
    if (off > ws_size) return;  // workspace too small; fail cleanly

    bf16* h1f[2] = {h1f0, h1f1};
    bf16* h1b[2] = {h1b0, h1b1};

    prep_kernel<<<dim3(2048, 6), 256, 0, stream>>>(wih0f, wih0b, whh0f, whh0b,
                                                   wih1f, whh1f, wih1b, whh1b,
                                                   wih0f_b, wih0b_b, whh0f_b, whh0b_b,
                                                   w1f_b, w1b_b);
    embed_kernel<<<4096, 128, 0, stream>>>(tok, tbl, X0);

    dim3 g(16, 8, 2), blk(512, 1, 1);

    // P0 = X0 @ wih0^T for both directions -> [4096 token][2048], col = u*4+gate
    {
        StepArgs f{}, b{};
        f.A1 = X0; f.W = wih0f_b; f.Hout = P0f;
        b = f; b.W = wih0b_b; b.Hout = P0b;
        step_pair<0><<<g, blk, 0, stream>>>(f, b);
    }

    const size_t SLOT = (size_t)4096 * 1024;

    // layer 0: fwd l=0..16 paired with bwd l=16..0
    for (int i = 0; i <= 16; ++i) {
        const int lf = i, lb = 16 - i;
        StepArgs f{}, b{};
        f.A1 = (lf == 0) ? (const bf16*)0 : X1 + (size_t)(lf - 1) * SLOT;
        f.W = whh0f_b; f.bias = b0f; f.P0 = P0f; f.Cst = c0f;
        f.Hout = X1 + (size_t)lf * SLOT; f.Hprev = f.A1;
        f.l = lf; f.firstStep = (lf == 0) ? 1 : 0;
        b.A1 = (lb == 16) ? (const bf16*)0 : X1 + (size_t)(lb + 1) * SLOT + 512;
        b.W = whh0b_b; b.bias = b0b; b.P0 = P0b; b.Cst = c0b;
        b.Hout = X1 + (size_t)lb * SLOT + 512; b.Hprev = b.A1;
        b.l = lb; b.firstStep = (lb == 16) ? 1 : 0;
        step_pair<1><<<g, blk, 0, stream>>>(f, b);
    }

    // layer 1: only steps needed for the center slot: fwd l=0..8, bwd l=16..8
    for (int i = 0; i <= 8; ++i) {
        const int lf = i, lb = 16 - i;
        StepArgs f{}, b{};
        f.A1 = X1 + (size_t)lf * SLOT;
        f.A2 = (i == 0) ? (const bf16*)0 : h1f[(i + 1) & 1];
        f.W = w1f_b; f.bias = b1f; f.Cst = c0f;  // c0f reused as layer-1 fwd cell state
        f.Hout = h1f[i & 1]; f.Hf32 = (i == 8) ? hf32f : (float*)0;
        f.Hprev = f.A2;
        f.l = lf; f.firstStep = (i == 0) ? 1 : 0;
        b.A1 = X1 + (size_t)lb * SLOT;
        b.A2 = (i == 0) ? (const bf16*)0 : h1b[(i + 1) & 1];
        b.W = w1b_b; b.bias = b1b; b.Cst = c0b;
        b.Hout = h1b[i & 1]; b.Hf32 = (i == 8) ? hf32b : (float*)0;
        b.Hprev = b.A2;
        b.l = lb; b.firstStep = (i == 0) ? 1 : 0;
        step_pair<2><<<g, blk, 0, stream>>>(f, b);
    }

    combine_kernel<<<2048, 256, 0, stream>>>(hf32f, hf32b, (float*)d_out);
}